// Round 13
// baseline (128.308 us; speedup 1.0000x reference)
//
#include <hip/hip_runtime.h>
#include <hip/hip_bf16.h>
#include <stdint.h>

#define NNODES 100000
#define DIN    256
#define DOUT   128
#define KNB    16
#define NTILES 1563          // ceil(100000/64)
#define GBLK   512           // GEMM grid: exactly 2 blocks/CU

typedef __attribute__((ext_vector_type(8))) __bf16 bf16x8;
typedef __attribute__((ext_vector_type(4))) float  f32x4;
typedef __attribute__((ext_vector_type(8))) unsigned short u16x8;
typedef __attribute__((ext_vector_type(4))) uint32_t u32x4;
typedef __attribute__((ext_vector_type(2))) uint32_t u32x2;

// ---------------------------------------------------------------------------
// Kernel 0: Wt[c][k] = bf16(W[k][c])  (128 x 256 bf16 = 64 KB, L2-resident)
// ---------------------------------------------------------------------------
__global__ __launch_bounds__(256)
void gc_wt(const float* __restrict__ W, unsigned short* __restrict__ Wt)
{
    const int idx = blockIdx.x * 256 + threadIdx.x;   // 0 .. 32767
    const int c = idx >> 8;        // 0..127
    const int k = idx & 255;       // 0..255
    Wt[c * DIN + k] = __builtin_bit_cast(unsigned short, (__bf16)W[k * DOUT + c]);
}

// ---------------------------------------------------------------------------
// Kernel 1: h = relu(feats @ W + b) -> bf16.  (R12 persistent pipeline —
// at ~3.7 TB/s L3-fabric rate with irreducible 128 MB; near its wall)
// ---------------------------------------------------------------------------
__global__ __launch_bounds__(256, 2)
void gc_linear_relu(const float* __restrict__ feats,
                    const unsigned short* __restrict__ Wt,
                    const float* __restrict__ bias,
                    unsigned short* __restrict__ h)
{
    __shared__ unsigned short As[2][64 * 256];   // 2 x 32 KB bf16, swizzled

    const int t    = threadIdx.x;
    const int lane = t & 63;
    const int wave = t >> 6;                  // 0..3
    const int wcol = wave * 32;
    const int fr   = lane & 15;
    const int kb   = lane >> 4;               // 0..3
    const int bid  = blockIdx.x;

    const int t0 = (int)(((long long)bid     * NTILES) >> 9);
    const int t1 = (int)(((long long)(bid+1) * NTILES) >> 9);

    int rr[8], cc[8];
    #pragma unroll
    for (int i = 0; i < 8; ++i) {
        const int id = i * 256 + t;
        rr[i] = id >> 5;
        const int c = id & 31;
        cc[i] = c ^ (rr[i] & 15);
    }

    u32x4 a0, a1, a2, a3, a4, a5, a6, a7, a8, a9, a10, a11, a12, a13, a14, a15;
    u32x4 p00, p01, p02, p03, p10, p11, p12, p13;
    u32x4 q00, q01, q02, q03, q10, q11, q12, q13;

#define ISSUE_A(brow)                                                          \
    {                                                                          \
        const float* base = feats;                                             \
        _Pragma("unroll")                                                      \
        for (int i = 0; i < 8; ++i) {                                          \
            int gr = (brow) + rr[i]; if (gr >= NNODES) gr = NNODES - 1;        \
            const float* ap = base + (size_t)gr * DIN + ((i * 256 + t) & 31) * 8; \
            u32x4* va; u32x4* vb;                                              \
            switch (i) {                                                       \
                case 0: va = &a0;  vb = &a1;  break;                           \
                case 1: va = &a2;  vb = &a3;  break;                           \
                case 2: va = &a4;  vb = &a5;  break;                           \
                case 3: va = &a6;  vb = &a7;  break;                           \
                case 4: va = &a8;  vb = &a9;  break;                           \
                case 5: va = &a10; vb = &a11; break;                           \
                case 6: va = &a12; vb = &a13; break;                           \
                default: va = &a14; vb = &a15; break;                          \
            }                                                                  \
            asm volatile("global_load_dwordx4 %0, %1, off" : "=v"(*va) : "v"(ap)); \
            asm volatile("global_load_dwordx4 %0, %1, off offset:16" : "=v"(*vb) : "v"(ap)); \
        }                                                                      \
    }

#define WAIT_A()                                                               \
    asm volatile("s_waitcnt vmcnt(0)"                                          \
                 : "+v"(a0), "+v"(a1), "+v"(a2),  "+v"(a3),                    \
                   "+v"(a4), "+v"(a5), "+v"(a6),  "+v"(a7),                    \
                   "+v"(a8), "+v"(a9), "+v"(a10), "+v"(a11),                   \
                   "+v"(a12), "+v"(a13), "+v"(a14), "+v"(a15)                  \
                 :: "memory");                                                 \
    __builtin_amdgcn_sched_barrier(0);

    ISSUE_A(t0 * 64)

    const unsigned short* wp0 = Wt + (wcol + fr) * DIN + kb * 8;
    const unsigned short* wp1 = wp0 + 16 * DIN;
    asm volatile("global_load_dwordx4 %0, %1, off"            : "=v"(p00) : "v"(wp0));
    asm volatile("global_load_dwordx4 %0, %1, off offset:64"  : "=v"(p01) : "v"(wp0));
    asm volatile("global_load_dwordx4 %0, %1, off offset:128" : "=v"(p02) : "v"(wp0));
    asm volatile("global_load_dwordx4 %0, %1, off offset:192" : "=v"(p03) : "v"(wp0));
    asm volatile("global_load_dwordx4 %0, %1, off"            : "=v"(p10) : "v"(wp1));
    asm volatile("global_load_dwordx4 %0, %1, off offset:64"  : "=v"(p11) : "v"(wp1));
    asm volatile("global_load_dwordx4 %0, %1, off offset:128" : "=v"(p12) : "v"(wp1));
    asm volatile("global_load_dwordx4 %0, %1, off offset:192" : "=v"(p13) : "v"(wp1));
    asm volatile("global_load_dwordx4 %0, %1, off offset:256" : "=v"(q00) : "v"(wp0));
    asm volatile("global_load_dwordx4 %0, %1, off offset:320" : "=v"(q01) : "v"(wp0));
    asm volatile("global_load_dwordx4 %0, %1, off offset:384" : "=v"(q02) : "v"(wp0));
    asm volatile("global_load_dwordx4 %0, %1, off offset:448" : "=v"(q03) : "v"(wp0));
    asm volatile("global_load_dwordx4 %0, %1, off offset:256" : "=v"(q10) : "v"(wp1));
    asm volatile("global_load_dwordx4 %0, %1, off offset:320" : "=v"(q11) : "v"(wp1));
    asm volatile("global_load_dwordx4 %0, %1, off offset:384" : "=v"(q12) : "v"(wp1));
    asm volatile("global_load_dwordx4 %0, %1, off offset:448" : "=v"(q13) : "v"(wp1));

    asm volatile("s_waitcnt vmcnt(0)"
                 : "+v"(a0), "+v"(a1), "+v"(a2),  "+v"(a3),
                   "+v"(a4), "+v"(a5), "+v"(a6),  "+v"(a7),
                   "+v"(a8), "+v"(a9), "+v"(a10), "+v"(a11),
                   "+v"(a12), "+v"(a13), "+v"(a14), "+v"(a15),
                   "+v"(p00), "+v"(p01), "+v"(p02), "+v"(p03),
                   "+v"(p10), "+v"(p11), "+v"(p12), "+v"(p13),
                   "+v"(q00), "+v"(q01), "+v"(q02), "+v"(q03),
                   "+v"(q10), "+v"(q11), "+v"(q12), "+v"(q13)
                 :: "memory");
    __builtin_amdgcn_sched_barrier(0);

    int buf = 0;
    for (int tile = t0; tile < t1; ++tile) {
        const int brow = tile * 64;
        const bool pf = (tile + 1 < t1);

#define SCVT(va, vb, i)                                                        \
        {                                                                      \
            const f32x4 x = __builtin_bit_cast(f32x4, va);                     \
            const f32x4 y = __builtin_bit_cast(f32x4, vb);                     \
            bf16x8 w;                                                          \
            w[0] = (__bf16)x[0]; w[1] = (__bf16)x[1];                          \
            w[2] = (__bf16)x[2]; w[3] = (__bf16)x[3];                          \
            w[4] = (__bf16)y[0]; w[5] = (__bf16)y[1];                          \
            w[6] = (__bf16)y[2]; w[7] = (__bf16)y[3];                          \
            *reinterpret_cast<bf16x8*>(&As[buf][rr[i] * 256 + cc[i] * 8]) = w; \
        }
        SCVT(a0,  a1,  0) SCVT(a2,  a3,  1) SCVT(a4,  a5,  2) SCVT(a6,  a7,  3)
        SCVT(a8,  a9,  4) SCVT(a10, a11, 5) SCVT(a12, a13, 6) SCVT(a14, a15, 7)
#undef SCVT

        asm volatile("s_waitcnt lgkmcnt(0)" ::: "memory");
        __builtin_amdgcn_s_barrier();

        if (pf) ISSUE_A(brow + 64)

        f32x4 acc[4][2];
        #pragma unroll
        for (int rt = 0; rt < 4; ++rt) {
            acc[rt][0] = (f32x4){0.f, 0.f, 0.f, 0.f};
            acc[rt][1] = (f32x4){0.f, 0.f, 0.f, 0.f};
        }

#define MFMA_K(wa, wb, ksl)                                                    \
        {                                                                      \
            _Pragma("unroll")                                                  \
            for (int rt = 0; rt < 4; ++rt) {                                   \
                const int row = rt * 16 + fr;                                  \
                const bf16x8 af = *reinterpret_cast<const bf16x8*>(            \
                    &As[buf][row * 256 + (((ksl) * 4 + kb) ^ fr) * 8]);        \
                acc[rt][0] = __builtin_amdgcn_mfma_f32_16x16x32_bf16(          \
                    __builtin_bit_cast(bf16x8, wa), af, acc[rt][0], 0, 0, 0);  \
                acc[rt][1] = __builtin_amdgcn_mfma_f32_16x16x32_bf16(          \
                    __builtin_bit_cast(bf16x8, wb), af, acc[rt][1], 0, 0, 0);  \
            }                                                                  \
        }
        MFMA_K(p00, p10, 0) MFMA_K(p01, p11, 1)
        MFMA_K(p02, p12, 2) MFMA_K(p03, p13, 3)
        MFMA_K(q00, q10, 4) MFMA_K(q01, q11, 5)
        MFMA_K(q02, q12, 6) MFMA_K(q03, q13, 7)
#undef MFMA_K

        #pragma unroll
        for (int rt = 0; rt < 4; ++rt) {
            const int grow = brow + rt * 16 + fr;
            if (grow < NNODES) {
                #pragma unroll
                for (int ct = 0; ct < 2; ++ct) {
                    const int colb = wcol + ct * 16 + kb * 4;
                    union { unsigned short us[4]; uint2 v; } o;
                    o.us[0] = __builtin_bit_cast(unsigned short, (__bf16)fmaxf(acc[rt][ct][0] + bias[colb + 0], 0.f));
                    o.us[1] = __builtin_bit_cast(unsigned short, (__bf16)fmaxf(acc[rt][ct][1] + bias[colb + 1], 0.f));
                    o.us[2] = __builtin_bit_cast(unsigned short, (__bf16)fmaxf(acc[rt][ct][2] + bias[colb + 2], 0.f));
                    o.us[3] = __builtin_bit_cast(unsigned short, (__bf16)fmaxf(acc[rt][ct][3] + bias[colb + 3], 0.f));
                    *reinterpret_cast<uint2*>(h + (size_t)grow * DOUT + colb) = o.v;
                }
            }
        }

        if (pf) WAIT_A()
        buf ^= 1;
    }
#undef ISSUE_A
#undef WAIT_A
}

// ---------------------------------------------------------------------------
// Kernel 2: XCD-affine column-panel gather.
// Grid 12500: panel = bid&3 (32 cols = 64B lines), chunk = bid>>2 (32 nodes).
// Dispatch round-robin => XCD x always gets panel x&3: per-XCD h working set
// 25.6 -> 6.4 MB (fits L2), replication FETCH drops ~173 -> ~100 MB.
// 8 lanes/node, 8B (4 bf16 cols) per lane; 16 forced-MLP dwordx2 loads.
// ---------------------------------------------------------------------------
__global__ __launch_bounds__(256, 4)
void gc_gather_panel(const int* __restrict__ edge,
                     const unsigned short* __restrict__ h,
                     float* __restrict__ out)
{
    const int t     = threadIdx.x;
    const int bid   = blockIdx.x;
    const int panel = bid & 3;            // 32-col panel; == XCD&3 under %8 rr
    const int chunk = bid >> 2;           // 0..3124
    const int nloc  = t >> 3;             // node within block, 0..31
    const int g8    = t & 7;              // 8B sub-column within panel
    const int node  = chunk * 32 + nloc;  // < 100000 exact
    const int gbase = (t & 63) & 56;      // 8-lane group base within wave

    const int e0 = edge[node * KNB + g8];       // lane g8 holds edges g8, g8+8
    const int e1 = edge[node * KNB + 8 + g8];

    const unsigned short* hp = h + panel * 32 + g8 * 4;   // +nb*128 per nb

    u32x2 w0, w1, w2, w3, w4, w5, w6, w7, w8, w9, w10, w11, w12, w13, w14, w15;

#define GL(wk, nb)                                                             \
    {                                                                          \
        const unsigned short* p = hp + (size_t)(nb) * DOUT;                    \
        asm volatile("global_load_dwordx2 %0, %1, off" : "=v"(wk) : "v"(p));   \
    }
    GL(w0,  __shfl(e0, gbase | 0)) GL(w1,  __shfl(e0, gbase | 1))
    GL(w2,  __shfl(e0, gbase | 2)) GL(w3,  __shfl(e0, gbase | 3))
    GL(w4,  __shfl(e0, gbase | 4)) GL(w5,  __shfl(e0, gbase | 5))
    GL(w6,  __shfl(e0, gbase | 6)) GL(w7,  __shfl(e0, gbase | 7))
    GL(w8,  __shfl(e1, gbase | 0)) GL(w9,  __shfl(e1, gbase | 1))
    GL(w10, __shfl(e1, gbase | 2)) GL(w11, __shfl(e1, gbase | 3))
    GL(w12, __shfl(e1, gbase | 4)) GL(w13, __shfl(e1, gbase | 5))
    GL(w14, __shfl(e1, gbase | 6)) GL(w15, __shfl(e1, gbase | 7))
#undef GL

    asm volatile("s_waitcnt vmcnt(0)"
                 : "+v"(w0), "+v"(w1), "+v"(w2),  "+v"(w3),
                   "+v"(w4), "+v"(w5), "+v"(w6),  "+v"(w7),
                   "+v"(w8), "+v"(w9), "+v"(w10), "+v"(w11),
                   "+v"(w12), "+v"(w13), "+v"(w14), "+v"(w15)
                 :
                 : "memory");
    __builtin_amdgcn_sched_barrier(0);

    float s0 = 0.f, s1 = 0.f, s2 = 0.f, s3 = 0.f;
#define ACC(wk)                                                                \
    {                                                                          \
        union { uint32_t u; float f; } lo, hi;                                 \
        lo.u = wk[0] << 16;          s0 += lo.f;                               \
        hi.u = wk[0] & 0xFFFF0000u;  s1 += hi.f;                               \
        lo.u = wk[1] << 16;          s2 += lo.f;                               \
        hi.u = wk[1] & 0xFFFF0000u;  s3 += hi.f;                               \
    }
    ACC(w0)  ACC(w1)  ACC(w2)  ACC(w3)
    ACC(w4)  ACC(w5)  ACC(w6)  ACC(w7)
    ACC(w8)  ACC(w9)  ACC(w10) ACC(w11)
    ACC(w12) ACC(w13) ACC(w14) ACC(w15)
#undef ACC

    f32x4 o = {s0 * 0.0625f, s1 * 0.0625f, s2 * 0.0625f, s3 * 0.0625f};
    float* op = out + (size_t)node * DOUT + panel * 32 + g8 * 4;
    __builtin_nontemporal_store(o, reinterpret_cast<f32x4*>(op));
}

extern "C" void kernel_launch(void* const* d_in, const int* in_sizes, int n_in,
                              void* d_out, int out_size, void* d_ws, size_t ws_size,
                              hipStream_t stream)
{
    const float* feats = (const float*)d_in[0];
    const int*   edge  = (const int*)d_in[1];
    const float* W     = (const float*)d_in[2];
    const float* bias  = (const float*)d_in[3];
    float* out = (float*)d_out;

    const size_t h_bytes  = (size_t)NNODES * DOUT * sizeof(unsigned short); // 25.6 MB
    const size_t wt_bytes = (size_t)DIN * DOUT * sizeof(unsigned short);    // 64 KB

    unsigned short* h = (unsigned short*)d_ws;
    unsigned short* Wt;
    if (ws_size >= h_bytes + wt_bytes)
        Wt = (unsigned short*)((char*)d_ws + h_bytes);
    else
        Wt = (unsigned short*)d_out;   // gather fully overwrites d_out later

    gc_wt<<<(DIN * DOUT) / 256, 256, 0, stream>>>(W, Wt);

    gc_linear_relu<<<GBLK, 256, 0, stream>>>(feats, Wt, bias, h);

    const int gat_blocks = (NNODES / 32) * 4;       // 12500: 4 panels x 3125
    gc_gather_panel<<<gat_blocks, 256, 0, stream>>>(edge, h, out);
}

// Round 14
// 72.260 us; speedup vs baseline: 1.7756x; 1.7756x over previous
//
#include <hip/hip_runtime.h>
#include <hip/hip_bf16.h>
#include <stdint.h>

#define NNODES 100000
#define DIN    256
#define DOUT   128
#define KNB    16
#define NTILES 1563          // ceil(100000/64)
#define GBLK   512           // GEMM grid: exactly 2 blocks/CU

typedef __attribute__((ext_vector_type(8))) __bf16 bf16x8;
typedef __attribute__((ext_vector_type(4))) float  f32x4;
typedef __attribute__((ext_vector_type(8))) unsigned short u16x8;
typedef __attribute__((ext_vector_type(4))) uint32_t u32x4;
typedef __attribute__((ext_vector_type(2))) uint32_t u32x2;

// ---------------------------------------------------------------------------
// Kernel 0: Wt[c][k] = bf16(W[k][c])  (128 x 256 bf16 = 64 KB, L2-resident)
// ---------------------------------------------------------------------------
__global__ __launch_bounds__(256)
void gc_wt(const float* __restrict__ W, unsigned short* __restrict__ Wt)
{
    const int idx = blockIdx.x * 256 + threadIdx.x;   // 0 .. 32767
    const int c = idx >> 8;        // 0..127
    const int k = idx & 255;       // 0..255
    Wt[c * DIN + k] = __builtin_bit_cast(unsigned short, (__bf16)W[k * DOUT + c]);
}

// ---------------------------------------------------------------------------
// Kernel 1: h8 = u8-quantized relu(feats @ W + b), per-row scale in hscale.
// R12 persistent pipeline + new quantizing epilogue:
//   per-rt rowmax: local max(8) -> shfl_xor(16,32) across kb -> LDS across
//   waves (rmaxs[4][64], 1KB) -> inv=255/rm -> pack 4 u8 per 4B store.
// Gather's h traffic halves (25.6 -> 13.2 MB inc. scales).
// ---------------------------------------------------------------------------
__global__ __launch_bounds__(256, 2)
void gc_linear_relu(const float* __restrict__ feats,
                    const unsigned short* __restrict__ Wt,
                    const float* __restrict__ bias,
                    unsigned char* __restrict__ h8,
                    float* __restrict__ hscale)
{
    __shared__ unsigned short As[2][64 * 256];   // 2 x 32 KB bf16, swizzled
    __shared__ float rmaxs[4][64];               // per-wave row maxima

    const int t    = threadIdx.x;
    const int lane = t & 63;
    const int wave = t >> 6;                  // 0..3
    const int wcol = wave * 32;
    const int fr   = lane & 15;
    const int kb   = lane >> 4;               // 0..3
    const int bid  = blockIdx.x;

    const int t0 = (int)(((long long)bid     * NTILES) >> 9);
    const int t1 = (int)(((long long)(bid+1) * NTILES) >> 9);

    int rr[8], cc[8];
    #pragma unroll
    for (int i = 0; i < 8; ++i) {
        const int id = i * 256 + t;
        rr[i] = id >> 5;
        const int c = id & 31;
        cc[i] = c ^ (rr[i] & 15);
    }

    u32x4 a0, a1, a2, a3, a4, a5, a6, a7, a8, a9, a10, a11, a12, a13, a14, a15;
    u32x4 p00, p01, p02, p03, p10, p11, p12, p13;
    u32x4 q00, q01, q02, q03, q10, q11, q12, q13;

#define ISSUE_A(brow)                                                          \
    {                                                                          \
        const float* base = feats;                                             \
        _Pragma("unroll")                                                      \
        for (int i = 0; i < 8; ++i) {                                          \
            int gr = (brow) + rr[i]; if (gr >= NNODES) gr = NNODES - 1;        \
            const float* ap = base + (size_t)gr * DIN + ((i * 256 + t) & 31) * 8; \
            u32x4* va; u32x4* vb;                                              \
            switch (i) {                                                       \
                case 0: va = &a0;  vb = &a1;  break;                           \
                case 1: va = &a2;  vb = &a3;  break;                           \
                case 2: va = &a4;  vb = &a5;  break;                           \
                case 3: va = &a6;  vb = &a7;  break;                           \
                case 4: va = &a8;  vb = &a9;  break;                           \
                case 5: va = &a10; vb = &a11; break;                           \
                case 6: va = &a12; vb = &a13; break;                           \
                default: va = &a14; vb = &a15; break;                          \
            }                                                                  \
            asm volatile("global_load_dwordx4 %0, %1, off" : "=v"(*va) : "v"(ap)); \
            asm volatile("global_load_dwordx4 %0, %1, off offset:16" : "=v"(*vb) : "v"(ap)); \
        }                                                                      \
    }

#define WAIT_A()                                                               \
    asm volatile("s_waitcnt vmcnt(0)"                                          \
                 : "+v"(a0), "+v"(a1), "+v"(a2),  "+v"(a3),                    \
                   "+v"(a4), "+v"(a5), "+v"(a6),  "+v"(a7),                    \
                   "+v"(a8), "+v"(a9), "+v"(a10), "+v"(a11),                   \
                   "+v"(a12), "+v"(a13), "+v"(a14), "+v"(a15)                  \
                 :: "memory");                                                 \
    __builtin_amdgcn_sched_barrier(0);

    ISSUE_A(t0 * 64)

    const unsigned short* wp0 = Wt + (wcol + fr) * DIN + kb * 8;
    const unsigned short* wp1 = wp0 + 16 * DIN;
    asm volatile("global_load_dwordx4 %0, %1, off"            : "=v"(p00) : "v"(wp0));
    asm volatile("global_load_dwordx4 %0, %1, off offset:64"  : "=v"(p01) : "v"(wp0));
    asm volatile("global_load_dwordx4 %0, %1, off offset:128" : "=v"(p02) : "v"(wp0));
    asm volatile("global_load_dwordx4 %0, %1, off offset:192" : "=v"(p03) : "v"(wp0));
    asm volatile("global_load_dwordx4 %0, %1, off"            : "=v"(p10) : "v"(wp1));
    asm volatile("global_load_dwordx4 %0, %1, off offset:64"  : "=v"(p11) : "v"(wp1));
    asm volatile("global_load_dwordx4 %0, %1, off offset:128" : "=v"(p12) : "v"(wp1));
    asm volatile("global_load_dwordx4 %0, %1, off offset:192" : "=v"(p13) : "v"(wp1));
    asm volatile("global_load_dwordx4 %0, %1, off offset:256" : "=v"(q00) : "v"(wp0));
    asm volatile("global_load_dwordx4 %0, %1, off offset:320" : "=v"(q01) : "v"(wp0));
    asm volatile("global_load_dwordx4 %0, %1, off offset:384" : "=v"(q02) : "v"(wp0));
    asm volatile("global_load_dwordx4 %0, %1, off offset:448" : "=v"(q03) : "v"(wp0));
    asm volatile("global_load_dwordx4 %0, %1, off offset:256" : "=v"(q10) : "v"(wp1));
    asm volatile("global_load_dwordx4 %0, %1, off offset:320" : "=v"(q11) : "v"(wp1));
    asm volatile("global_load_dwordx4 %0, %1, off offset:384" : "=v"(q12) : "v"(wp1));
    asm volatile("global_load_dwordx4 %0, %1, off offset:448" : "=v"(q13) : "v"(wp1));

    asm volatile("s_waitcnt vmcnt(0)"
                 : "+v"(a0), "+v"(a1), "+v"(a2),  "+v"(a3),
                   "+v"(a4), "+v"(a5), "+v"(a6),  "+v"(a7),
                   "+v"(a8), "+v"(a9), "+v"(a10), "+v"(a11),
                   "+v"(a12), "+v"(a13), "+v"(a14), "+v"(a15),
                   "+v"(p00), "+v"(p01), "+v"(p02), "+v"(p03),
                   "+v"(p10), "+v"(p11), "+v"(p12), "+v"(p13),
                   "+v"(q00), "+v"(q01), "+v"(q02), "+v"(q03),
                   "+v"(q10), "+v"(q11), "+v"(q12), "+v"(q13)
                 :: "memory");
    __builtin_amdgcn_sched_barrier(0);

    int buf = 0;
    for (int tile = t0; tile < t1; ++tile) {
        const int brow = tile * 64;
        const bool pf = (tile + 1 < t1);

#define SCVT(va, vb, i)                                                        \
        {                                                                      \
            const f32x4 x = __builtin_bit_cast(f32x4, va);                     \
            const f32x4 y = __builtin_bit_cast(f32x4, vb);                     \
            bf16x8 w;                                                          \
            w[0] = (__bf16)x[0]; w[1] = (__bf16)x[1];                          \
            w[2] = (__bf16)x[2]; w[3] = (__bf16)x[3];                          \
            w[4] = (__bf16)y[0]; w[5] = (__bf16)y[1];                          \
            w[6] = (__bf16)y[2]; w[7] = (__bf16)y[3];                          \
            *reinterpret_cast<bf16x8*>(&As[buf][rr[i] * 256 + cc[i] * 8]) = w; \
        }
        SCVT(a0,  a1,  0) SCVT(a2,  a3,  1) SCVT(a4,  a5,  2) SCVT(a6,  a7,  3)
        SCVT(a8,  a9,  4) SCVT(a10, a11, 5) SCVT(a12, a13, 6) SCVT(a14, a15, 7)
#undef SCVT

        asm volatile("s_waitcnt lgkmcnt(0)" ::: "memory");
        __builtin_amdgcn_s_barrier();

        if (pf) ISSUE_A(brow + 64)

        f32x4 acc[4][2];
        #pragma unroll
        for (int rt = 0; rt < 4; ++rt) {
            acc[rt][0] = (f32x4){0.f, 0.f, 0.f, 0.f};
            acc[rt][1] = (f32x4){0.f, 0.f, 0.f, 0.f};
        }

#define MFMA_K(wa, wb, ksl)                                                    \
        {                                                                      \
            _Pragma("unroll")                                                  \
            for (int rt = 0; rt < 4; ++rt) {                                   \
                const int row = rt * 16 + fr;                                  \
                const bf16x8 af = *reinterpret_cast<const bf16x8*>(            \
                    &As[buf][row * 256 + (((ksl) * 4 + kb) ^ fr) * 8]);        \
                acc[rt][0] = __builtin_amdgcn_mfma_f32_16x16x32_bf16(          \
                    __builtin_bit_cast(bf16x8, wa), af, acc[rt][0], 0, 0, 0);  \
                acc[rt][1] = __builtin_amdgcn_mfma_f32_16x16x32_bf16(          \
                    __builtin_bit_cast(bf16x8, wb), af, acc[rt][1], 0, 0, 0);  \
            }                                                                  \
        }
        MFMA_K(p00, p10, 0) MFMA_K(p01, p11, 1)
        MFMA_K(p02, p12, 2) MFMA_K(p03, p13, 3)
        MFMA_K(q00, q10, 4) MFMA_K(q01, q11, 5)
        MFMA_K(q02, q12, 6) MFMA_K(q03, q13, 7)
#undef MFMA_K

        // ---- epilogue: +bias, relu, per-row u8 quantization ----
        float vals[4][8];
        float rmx[4];
        #pragma unroll
        for (int rt = 0; rt < 4; ++rt) {
            float m = 0.f;
            #pragma unroll
            for (int ct = 0; ct < 2; ++ct) {
                const int colb = wcol + ct * 16 + kb * 4;
                #pragma unroll
                for (int r = 0; r < 4; ++r) {
                    const float v = fmaxf(acc[rt][ct][r] + bias[colb + r], 0.f);
                    vals[rt][ct * 4 + r] = v;
                    m = fmaxf(m, v);
                }
            }
            // row = rt*16+fr lives on lanes fr, fr+16, fr+32, fr+48 (kb axis)
            m = fmaxf(m, __shfl_xor(m, 16));
            m = fmaxf(m, __shfl_xor(m, 32));
            rmx[rt] = m;                      // wave-local rowmax (32 cols)
        }
        if (kb == 0) {
            #pragma unroll
            for (int rt = 0; rt < 4; ++rt)
                rmaxs[wave][rt * 16 + fr] = rmx[rt];
        }
        asm volatile("s_waitcnt lgkmcnt(0)" ::: "memory");
        __builtin_amdgcn_s_barrier();

        #pragma unroll
        for (int rt = 0; rt < 4; ++rt) {
            const int row  = rt * 16 + fr;
            const int grow = brow + row;
            const float rm = fmaxf(fmaxf(rmaxs[0][row], rmaxs[1][row]),
                                   fmaxf(rmaxs[2][row], rmaxs[3][row]));
            const float inv = rm > 0.f ? 255.f / rm : 0.f;
            if (grow < NNODES) {
                if (wave == 0 && kb == 0) hscale[grow] = rm * (1.f / 255.f);
                #pragma unroll
                for (int ct = 0; ct < 2; ++ct) {
                    const int colb = wcol + ct * 16 + kb * 4;
                    uint32_t q = 0;
                    #pragma unroll
                    for (int r = 0; r < 4; ++r) {
                        uint32_t qi = (uint32_t)(vals[rt][ct * 4 + r] * inv + 0.5f);
                        if (qi > 255u) qi = 255u;
                        q |= qi << (8 * r);
                    }
                    *reinterpret_cast<uint32_t*>(h8 + (size_t)grow * DOUT + colb) = q;
                }
            }
        }

        if (pf) WAIT_A()
        buf ^= 1;
    }
#undef ISSUE_A
#undef WAIT_A
}

// ---------------------------------------------------------------------------
// Kernel 2: out[i][:] = mean_k hscale[e]*h8[e][:]   (u8 h: half the fill
// traffic of bf16). 16 nodes/block, 16 lanes/node, 8 u8 cols (8B) per lane.
// Forced-MLP asm loads (R8 idiom); scales shfl-broadcast like indices.
// ---------------------------------------------------------------------------
__global__ __launch_bounds__(256, 4)
void gc_gather_mean(const int* __restrict__ edge,
                    const unsigned char* __restrict__ h8,
                    const float* __restrict__ hscale,
                    float* __restrict__ out)
{
    const int t    = threadIdx.x;
    const int grp  = t >> 4;          // node within block (0..15)
    const int c4   = t & 15;          // 8-col chunk within row == k index
    const int node = blockIdx.x * 16 + grp;
    const int gbase = (t & 63) & 48;  // 16-lane group base within wave

    const int   nb_mine = edge[node * KNB + c4];
    const float sc_mine = hscale[nb_mine];

    u32x2 w0, w1, w2, w3, w4, w5, w6, w7, w8, w9, w10, w11, w12, w13, w14, w15;

#define GL(wk, kidx)                                                           \
    {                                                                          \
        const unsigned char* p =                                               \
            h8 + (size_t)__shfl(nb_mine, gbase | (kidx)) * DOUT + c4 * 8;      \
        asm volatile("global_load_dwordx2 %0, %1, off" : "=v"(wk) : "v"(p));   \
    }
    GL(w0, 0)   GL(w1, 1)   GL(w2, 2)   GL(w3, 3)
    GL(w4, 4)   GL(w5, 5)   GL(w6, 6)   GL(w7, 7)
    GL(w8, 8)   GL(w9, 9)   GL(w10, 10) GL(w11, 11)
    GL(w12, 12) GL(w13, 13) GL(w14, 14) GL(w15, 15)
#undef GL

    asm volatile("s_waitcnt vmcnt(0)"
                 : "+v"(w0), "+v"(w1), "+v"(w2),  "+v"(w3),
                   "+v"(w4), "+v"(w5), "+v"(w6),  "+v"(w7),
                   "+v"(w8), "+v"(w9), "+v"(w10), "+v"(w11),
                   "+v"(w12), "+v"(w13), "+v"(w14), "+v"(w15)
                 :
                 : "memory");
    __builtin_amdgcn_sched_barrier(0);

    float s0 = 0.f, s1 = 0.f, s2 = 0.f, s3 = 0.f;
    float s4 = 0.f, s5 = 0.f, s6 = 0.f, s7 = 0.f;

#define ACCQ(wk, kidx)                                                         \
    {                                                                          \
        const float sc = __shfl(sc_mine, gbase | (kidx));                      \
        s0 += sc * (float)( wk[0]        & 0xffu);                             \
        s1 += sc * (float)((wk[0] >>  8) & 0xffu);                             \
        s2 += sc * (float)((wk[0] >> 16) & 0xffu);                             \
        s3 += sc * (float)( wk[0] >> 24        );                              \
        s4 += sc * (float)( wk[1]        & 0xffu);                             \
        s5 += sc * (float)((wk[1] >>  8) & 0xffu);                             \
        s6 += sc * (float)((wk[1] >> 16) & 0xffu);                             \
        s7 += sc * (float)( wk[1] >> 24        );                              \
    }
    ACCQ(w0, 0)   ACCQ(w1, 1)   ACCQ(w2, 2)   ACCQ(w3, 3)
    ACCQ(w4, 4)   ACCQ(w5, 5)   ACCQ(w6, 6)   ACCQ(w7, 7)
    ACCQ(w8, 8)   ACCQ(w9, 9)   ACCQ(w10, 10) ACCQ(w11, 11)
    ACCQ(w12, 12) ACCQ(w13, 13) ACCQ(w14, 14) ACCQ(w15, 15)
#undef ACCQ

    float* op = out + (size_t)node * DOUT + c4 * 8;
    f32x4 o0 = {s0 * 0.0625f, s1 * 0.0625f, s2 * 0.0625f, s3 * 0.0625f};
    f32x4 o1 = {s4 * 0.0625f, s5 * 0.0625f, s6 * 0.0625f, s7 * 0.0625f};
    __builtin_nontemporal_store(o0, reinterpret_cast<f32x4*>(op));
    __builtin_nontemporal_store(o1, reinterpret_cast<f32x4*>(op + 4));
}

extern "C" void kernel_launch(void* const* d_in, const int* in_sizes, int n_in,
                              void* d_out, int out_size, void* d_ws, size_t ws_size,
                              hipStream_t stream)
{
    const float* feats = (const float*)d_in[0];
    const int*   edge  = (const int*)d_in[1];
    const float* W     = (const float*)d_in[2];
    const float* bias  = (const float*)d_in[3];
    float* out = (float*)d_out;

    const size_t h8_bytes = (size_t)NNODES * DOUT;                 // 12.8 MB
    const size_t sc_bytes = (size_t)NNODES * sizeof(float);        // 0.4 MB
    const size_t wt_bytes = (size_t)DIN * DOUT * sizeof(unsigned short); // 64 KB

    unsigned char* h8     = (unsigned char*)d_ws;
    float*         hscale = (float*)((char*)d_ws + h8_bytes);
    unsigned short* Wt;
    if (ws_size >= h8_bytes + sc_bytes + wt_bytes)
        Wt = (unsigned short*)((char*)d_ws + h8_bytes + sc_bytes);
    else
        Wt = (unsigned short*)d_out;   // gather fully overwrites d_out later

    gc_wt<<<(DIN * DOUT) / 256, 256, 0, stream>>>(W, Wt);

    gc_linear_relu<<<GBLK, 256, 0, stream>>>(feats, Wt, bias, h8, hscale);

    const int gat_blocks = NNODES / 16;             // 6250, exact
    gc_gather_mean<<<gat_blocks, 256, 0, stream>>>(edge, h8, hscale, out);
}

// Round 16
// 72.100 us; speedup vs baseline: 1.7796x; 1.0022x over previous
//
#include <hip/hip_runtime.h>
#include <hip/hip_bf16.h>
#include <stdint.h>

#define NNODES 100000
#define DIN    256
#define DOUT   128
#define KNB    16
#define NTILES 1563          // ceil(100000/64)
#define GBLK   512           // GEMM grid: exactly 2 blocks/CU

typedef __attribute__((ext_vector_type(8))) __bf16 bf16x8;
typedef __attribute__((ext_vector_type(4))) float  f32x4;
typedef __attribute__((ext_vector_type(8))) unsigned short u16x8;
typedef __attribute__((ext_vector_type(4))) uint32_t u32x4;
typedef __attribute__((ext_vector_type(2))) uint32_t u32x2;

// ---------------------------------------------------------------------------
// Kernel 0: Wt[c][k] = bf16(W[k][c])  (128 x 256 bf16 = 64 KB, L2-resident)
// ---------------------------------------------------------------------------
__global__ __launch_bounds__(256)
void gc_wt(const float* __restrict__ W, unsigned short* __restrict__ Wt)
{
    const int idx = blockIdx.x * 256 + threadIdx.x;   // 0 .. 32767
    const int c = idx >> 8;        // 0..127
    const int k = idx & 255;       // 0..255
    Wt[c * DIN + k] = __builtin_bit_cast(unsigned short, (__bf16)W[k * DOUT + c]);
}

// ---------------------------------------------------------------------------
// Kernel 1: h8 = u8-quantized relu(feats @ W + b), per-row scale in hscale.
// R14 config (launch_bounds(256,2) — REQUIRED: the kernel needs ~220 VGPRs;
// (256,3)'s ~170 cap forced spills of in-flight asm-load destination regs,
// which read the VGPR without waitcnt -> NaN (R15). Double-buffered LDS.
// ---------------------------------------------------------------------------
__global__ __launch_bounds__(256, 2)
void gc_linear_relu(const float* __restrict__ feats,
                    const unsigned short* __restrict__ Wt,
                    const float* __restrict__ bias,
                    unsigned char* __restrict__ h8,
                    float* __restrict__ hscale)
{
    __shared__ unsigned short As[2][64 * 256];   // 2 x 32 KB bf16, swizzled
    __shared__ float rmaxs[4][64];               // per-wave row maxima

    const int t    = threadIdx.x;
    const int lane = t & 63;
    const int wave = t >> 6;                  // 0..3
    const int wcol = wave * 32;
    const int fr   = lane & 15;
    const int kb   = lane >> 4;               // 0..3
    const int bid  = blockIdx.x;

    const int t0 = (int)(((long long)bid     * NTILES) >> 9);
    const int t1 = (int)(((long long)(bid+1) * NTILES) >> 9);

    int rr[8], cc[8];
    #pragma unroll
    for (int i = 0; i < 8; ++i) {
        const int id = i * 256 + t;
        rr[i] = id >> 5;
        const int c = id & 31;
        cc[i] = c ^ (rr[i] & 15);
    }

    u32x4 a0, a1, a2, a3, a4, a5, a6, a7, a8, a9, a10, a11, a12, a13, a14, a15;
    u32x4 p00, p01, p02, p03, p10, p11, p12, p13;
    u32x4 q00, q01, q02, q03, q10, q11, q12, q13;

#define ISSUE_A(brow)                                                          \
    {                                                                          \
        const float* base = feats;                                             \
        _Pragma("unroll")                                                      \
        for (int i = 0; i < 8; ++i) {                                          \
            int gr = (brow) + rr[i]; if (gr >= NNODES) gr = NNODES - 1;        \
            const float* ap = base + (size_t)gr * DIN + ((i * 256 + t) & 31) * 8; \
            u32x4* va; u32x4* vb;                                              \
            switch (i) {                                                       \
                case 0: va = &a0;  vb = &a1;  break;                           \
                case 1: va = &a2;  vb = &a3;  break;                           \
                case 2: va = &a4;  vb = &a5;  break;                           \
                case 3: va = &a6;  vb = &a7;  break;                           \
                case 4: va = &a8;  vb = &a9;  break;                           \
                case 5: va = &a10; vb = &a11; break;                           \
                case 6: va = &a12; vb = &a13; break;                           \
                default: va = &a14; vb = &a15; break;                          \
            }                                                                  \
            asm volatile("global_load_dwordx4 %0, %1, off" : "=v"(*va) : "v"(ap)); \
            asm volatile("global_load_dwordx4 %0, %1, off offset:16" : "=v"(*vb) : "v"(ap)); \
        }                                                                      \
    }

#define WAIT_A()                                                               \
    asm volatile("s_waitcnt vmcnt(0)"                                          \
                 : "+v"(a0), "+v"(a1), "+v"(a2),  "+v"(a3),                    \
                   "+v"(a4), "+v"(a5), "+v"(a6),  "+v"(a7),                    \
                   "+v"(a8), "+v"(a9), "+v"(a10), "+v"(a11),                   \
                   "+v"(a12), "+v"(a13), "+v"(a14), "+v"(a15)                  \
                 :: "memory");                                                 \
    __builtin_amdgcn_sched_barrier(0);

    ISSUE_A(t0 * 64)

    const unsigned short* wp0 = Wt + (wcol + fr) * DIN + kb * 8;
    const unsigned short* wp1 = wp0 + 16 * DIN;
    asm volatile("global_load_dwordx4 %0, %1, off"            : "=v"(p00) : "v"(wp0));
    asm volatile("global_load_dwordx4 %0, %1, off offset:64"  : "=v"(p01) : "v"(wp0));
    asm volatile("global_load_dwordx4 %0, %1, off offset:128" : "=v"(p02) : "v"(wp0));
    asm volatile("global_load_dwordx4 %0, %1, off offset:192" : "=v"(p03) : "v"(wp0));
    asm volatile("global_load_dwordx4 %0, %1, off"            : "=v"(p10) : "v"(wp1));
    asm volatile("global_load_dwordx4 %0, %1, off offset:64"  : "=v"(p11) : "v"(wp1));
    asm volatile("global_load_dwordx4 %0, %1, off offset:128" : "=v"(p12) : "v"(wp1));
    asm volatile("global_load_dwordx4 %0, %1, off offset:192" : "=v"(p13) : "v"(wp1));
    asm volatile("global_load_dwordx4 %0, %1, off offset:256" : "=v"(q00) : "v"(wp0));
    asm volatile("global_load_dwordx4 %0, %1, off offset:320" : "=v"(q01) : "v"(wp0));
    asm volatile("global_load_dwordx4 %0, %1, off offset:384" : "=v"(q02) : "v"(wp0));
    asm volatile("global_load_dwordx4 %0, %1, off offset:448" : "=v"(q03) : "v"(wp0));
    asm volatile("global_load_dwordx4 %0, %1, off offset:256" : "=v"(q10) : "v"(wp1));
    asm volatile("global_load_dwordx4 %0, %1, off offset:320" : "=v"(q11) : "v"(wp1));
    asm volatile("global_load_dwordx4 %0, %1, off offset:384" : "=v"(q12) : "v"(wp1));
    asm volatile("global_load_dwordx4 %0, %1, off offset:448" : "=v"(q13) : "v"(wp1));

    asm volatile("s_waitcnt vmcnt(0)"
                 : "+v"(a0), "+v"(a1), "+v"(a2),  "+v"(a3),
                   "+v"(a4), "+v"(a5), "+v"(a6),  "+v"(a7),
                   "+v"(a8), "+v"(a9), "+v"(a10), "+v"(a11),
                   "+v"(a12), "+v"(a13), "+v"(a14), "+v"(a15),
                   "+v"(p00), "+v"(p01), "+v"(p02), "+v"(p03),
                   "+v"(p10), "+v"(p11), "+v"(p12), "+v"(p13),
                   "+v"(q00), "+v"(q01), "+v"(q02), "+v"(q03),
                   "+v"(q10), "+v"(q11), "+v"(q12), "+v"(q13)
                 :: "memory");
    __builtin_amdgcn_sched_barrier(0);

    int buf = 0;
    for (int tile = t0; tile < t1; ++tile) {
        const int brow = tile * 64;
        const bool pf = (tile + 1 < t1);

#define SCVT(va, vb, i)                                                        \
        {                                                                      \
            const f32x4 x = __builtin_bit_cast(f32x4, va);                     \
            const f32x4 y = __builtin_bit_cast(f32x4, vb);                     \
            bf16x8 w;                                                          \
            w[0] = (__bf16)x[0]; w[1] = (__bf16)x[1];                          \
            w[2] = (__bf16)x[2]; w[3] = (__bf16)x[3];                          \
            w[4] = (__bf16)y[0]; w[5] = (__bf16)y[1];                          \
            w[6] = (__bf16)y[2]; w[7] = (__bf16)y[3];                          \
            *reinterpret_cast<bf16x8*>(&As[buf][rr[i] * 256 + cc[i] * 8]) = w; \
        }
        SCVT(a0,  a1,  0) SCVT(a2,  a3,  1) SCVT(a4,  a5,  2) SCVT(a6,  a7,  3)
        SCVT(a8,  a9,  4) SCVT(a10, a11, 5) SCVT(a12, a13, 6) SCVT(a14, a15, 7)
#undef SCVT

        asm volatile("s_waitcnt lgkmcnt(0)" ::: "memory");
        __builtin_amdgcn_s_barrier();

        if (pf) ISSUE_A(brow + 64)

        f32x4 acc[4][2];
        #pragma unroll
        for (int rt = 0; rt < 4; ++rt) {
            acc[rt][0] = (f32x4){0.f, 0.f, 0.f, 0.f};
            acc[rt][1] = (f32x4){0.f, 0.f, 0.f, 0.f};
        }

#define MFMA_K(wa, wb, ksl)                                                    \
        {                                                                      \
            _Pragma("unroll")                                                  \
            for (int rt = 0; rt < 4; ++rt) {                                   \
                const int row = rt * 16 + fr;                                  \
                const bf16x8 af = *reinterpret_cast<const bf16x8*>(            \
                    &As[buf][row * 256 + (((ksl) * 4 + kb) ^ fr) * 8]);        \
                acc[rt][0] = __builtin_amdgcn_mfma_f32_16x16x32_bf16(          \
                    __builtin_bit_cast(bf16x8, wa), af, acc[rt][0], 0, 0, 0);  \
                acc[rt][1] = __builtin_amdgcn_mfma_f32_16x16x32_bf16(          \
                    __builtin_bit_cast(bf16x8, wb), af, acc[rt][1], 0, 0, 0);  \
            }                                                                  \
        }
        MFMA_K(p00, p10, 0) MFMA_K(p01, p11, 1)
        MFMA_K(p02, p12, 2) MFMA_K(p03, p13, 3)
        MFMA_K(q00, q10, 4) MFMA_K(q01, q11, 5)
        MFMA_K(q02, q12, 6) MFMA_K(q03, q13, 7)
#undef MFMA_K

        // ---- epilogue: +bias, relu, per-row u8 quantization ----
        float vals[4][8];
        float rmx[4];
        #pragma unroll
        for (int rt = 0; rt < 4; ++rt) {
            float m = 0.f;
            #pragma unroll
            for (int ct = 0; ct < 2; ++ct) {
                const int colb = wcol + ct * 16 + kb * 4;
                #pragma unroll
                for (int r = 0; r < 4; ++r) {
                    const float v = fmaxf(acc[rt][ct][r] + bias[colb + r], 0.f);
                    vals[rt][ct * 4 + r] = v;
                    m = fmaxf(m, v);
                }
            }
            // row = rt*16+fr lives on lanes fr, fr+16, fr+32, fr+48 (kb axis)
            m = fmaxf(m, __shfl_xor(m, 16));
            m = fmaxf(m, __shfl_xor(m, 32));
            rmx[rt] = m;                      // wave-local rowmax (32 cols)
        }
        if (kb == 0) {
            #pragma unroll
            for (int rt = 0; rt < 4; ++rt)
                rmaxs[wave][rt * 16 + fr] = rmx[rt];
        }
        asm volatile("s_waitcnt lgkmcnt(0)" ::: "memory");
        __builtin_amdgcn_s_barrier();

        #pragma unroll
        for (int rt = 0; rt < 4; ++rt) {
            const int row  = rt * 16 + fr;
            const int grow = brow + row;
            const float rm = fmaxf(fmaxf(rmaxs[0][row], rmaxs[1][row]),
                                   fmaxf(rmaxs[2][row], rmaxs[3][row]));
            const float inv = rm > 0.f ? 255.f / rm : 0.f;
            if (grow < NNODES) {
                if (wave == 0 && kb == 0) hscale[grow] = rm * (1.f / 255.f);
                #pragma unroll
                for (int ct = 0; ct < 2; ++ct) {
                    const int colb = wcol + ct * 16 + kb * 4;
                    uint32_t q = 0;
                    #pragma unroll
                    for (int r = 0; r < 4; ++r) {
                        uint32_t qi = (uint32_t)(vals[rt][ct * 4 + r] * inv + 0.5f);
                        if (qi > 255u) qi = 255u;
                        q |= qi << (8 * r);
                    }
                    *reinterpret_cast<uint32_t*>(h8 + (size_t)grow * DOUT + colb) = q;
                }
            }
        }

        if (pf) WAIT_A()
        buf ^= 1;
    }
#undef ISSUE_A
#undef WAIT_A
}

// ---------------------------------------------------------------------------
// Kernel 2: out[i][:] = mean_k hscale[e]*h8[e][:]   (u8 h: half the fill
// traffic of bf16). 16 nodes/block, 16 lanes/node, 8 u8 cols (8B) per lane.
// Forced-MLP asm loads (R8 idiom); scales shfl-broadcast like indices.
// ---------------------------------------------------------------------------
__global__ __launch_bounds__(256, 4)
void gc_gather_mean(const int* __restrict__ edge,
                    const unsigned char* __restrict__ h8,
                    const float* __restrict__ hscale,
                    float* __restrict__ out)
{
    const int t    = threadIdx.x;
    const int grp  = t >> 4;          // node within block (0..15)
    const int c4   = t & 15;          // 8-col chunk within row == k index
    const int node = blockIdx.x * 16 + grp;
    const int gbase = (t & 63) & 48;  // 16-lane group base within wave

    const int   nb_mine = edge[node * KNB + c4];
    const float sc_mine = hscale[nb_mine];

    u32x2 w0, w1, w2, w3, w4, w5, w6, w7, w8, w9, w10, w11, w12, w13, w14, w15;

#define GL(wk, kidx)                                                           \
    {                                                                          \
        const unsigned char* p =                                               \
            h8 + (size_t)__shfl(nb_mine, gbase | (kidx)) * DOUT + c4 * 8;      \
        asm volatile("global_load_dwordx2 %0, %1, off" : "=v"(wk) : "v"(p));   \
    }
    GL(w0, 0)   GL(w1, 1)   GL(w2, 2)   GL(w3, 3)
    GL(w4, 4)   GL(w5, 5)   GL(w6, 6)   GL(w7, 7)
    GL(w8, 8)   GL(w9, 9)   GL(w10, 10) GL(w11, 11)
    GL(w12, 12) GL(w13, 13) GL(w14, 14) GL(w15, 15)
#undef GL

    asm volatile("s_waitcnt vmcnt(0)"
                 : "+v"(w0), "+v"(w1), "+v"(w2),  "+v"(w3),
                   "+v"(w4), "+v"(w5), "+v"(w6),  "+v"(w7),
                   "+v"(w8), "+v"(w9), "+v"(w10), "+v"(w11),
                   "+v"(w12), "+v"(w13), "+v"(w14), "+v"(w15)
                 :
                 : "memory");
    __builtin_amdgcn_sched_barrier(0);

    float s0 = 0.f, s1 = 0.f, s2 = 0.f, s3 = 0.f;
    float s4 = 0.f, s5 = 0.f, s6 = 0.f, s7 = 0.f;

#define ACCQ(wk, kidx)                                                         \
    {                                                                          \
        const float sc = __shfl(sc_mine, gbase | (kidx));                      \
        s0 += sc * (float)( wk[0]        & 0xffu);                             \
        s1 += sc * (float)((wk[0] >>  8) & 0xffu);                             \
        s2 += sc * (float)((wk[0] >> 16) & 0xffu);                             \
        s3 += sc * (float)( wk[0] >> 24        );                              \
        s4 += sc * (float)( wk[1]        & 0xffu);                             \
        s5 += sc * (float)((wk[1] >>  8) & 0xffu);                             \
        s6 += sc * (float)((wk[1] >> 16) & 0xffu);                             \
        s7 += sc * (float)( wk[1] >> 24        );                              \
    }
    ACCQ(w0, 0)   ACCQ(w1, 1)   ACCQ(w2, 2)   ACCQ(w3, 3)
    ACCQ(w4, 4)   ACCQ(w5, 5)   ACCQ(w6, 6)   ACCQ(w7, 7)
    ACCQ(w8, 8)   ACCQ(w9, 9)   ACCQ(w10, 10) ACCQ(w11, 11)
    ACCQ(w12, 12) ACCQ(w13, 13) ACCQ(w14, 14) ACCQ(w15, 15)
#undef ACCQ

    float* op = out + (size_t)node * DOUT + c4 * 8;
    f32x4 o0 = {s0 * 0.0625f, s1 * 0.0625f, s2 * 0.0625f, s3 * 0.0625f};
    f32x4 o1 = {s4 * 0.0625f, s5 * 0.0625f, s6 * 0.0625f, s7 * 0.0625f};
    __builtin_nontemporal_store(o0, reinterpret_cast<f32x4*>(op));
    __builtin_nontemporal_store(o1, reinterpret_cast<f32x4*>(op + 4));
}

extern "C" void kernel_launch(void* const* d_in, const int* in_sizes, int n_in,
                              void* d_out, int out_size, void* d_ws, size_t ws_size,
                              hipStream_t stream)
{
    const float* feats = (const float*)d_in[0];
    const int*   edge  = (const int*)d_in[1];
    const float* W     = (const float*)d_in[2];
    const float* bias  = (const float*)d_in[3];
    float* out = (float*)d_out;

    const size_t h8_bytes = (size_t)NNODES * DOUT;                 // 12.8 MB
    const size_t sc_bytes = (size_t)NNODES * sizeof(float);        // 0.4 MB
    const size_t wt_bytes = (size_t)DIN * DOUT * sizeof(unsigned short); // 64 KB

    unsigned char* h8     = (unsigned char*)d_ws;
    float*         hscale = (float*)((char*)d_ws + h8_bytes);
    unsigned short* Wt;
    if (ws_size >= h8_bytes + sc_bytes + wt_bytes)
        Wt = (unsigned short*)((char*)d_ws + h8_bytes + sc_bytes);
    else
        Wt = (unsigned short*)d_out;   // gather fully overwrites d_out later

    gc_wt<<<(DIN * DOUT) / 256, 256, 0, stream>>>(W, Wt);

    gc_linear_relu<<<GBLK, 256, 0, stream>>>(feats, Wt, bias, h8, hscale);

    const int gat_blocks = NNODES / 16;             // 6250, exact
    gc_gather_mean<<<gat_blocks, 256, 0, stream>>>(edge, h8, hscale, out);
}